// Round 12
// baseline (1110.589 us; speedup 1.0000x reference)
//
#include <hip/hip_runtime.h>
#include <stdint.h>

// Dense MFMA reformulation. out = leaky(A @ (B @ (B^T @ (A^T @ E)))).
// Intermediates kept TRANSPOSED: X[d][*] (256 x 8192, bf16). Then:
//   G1: X1[d][e] = sum_n XT0[d][n] * A[n][e]   (NN, W = A fp32)
//   G2: X2[d][n] = sum_e X1[d][e]  * B[e][n]   (NN, W = B)
//   G3: X3[d][e] = sum_n X2[d][n]  * B[e][n]   (NT, W = B)
//   G4: C4[d][n] = sum_e X3[d][e]  * A[n][e]   (NT, W = A); out[n][d] = leaky(C4[d][n])
// GEMM: M=256 (full), Nt=64, K split 2 (grid 128x2 = 256 blocks, 1/CU).
// W is read fp32 directly and converted to bf16 during LDS staging (W read
// exactly once per GEMM = 256 MB; total W traffic 1.02 GB — the roofline term).

#define KC 64          // K-chunk per stage
#define KP 72          // padded LDS row stride in bf16 elems (144 B, 16B-aligned)
#define MROWS 256
#define NBIG 8192
#define PHALF (MROWS * NBIG)   // elems in one K-split partial (2,097,152)

typedef short  short8 __attribute__((ext_vector_type(8)));
typedef float  float4v __attribute__((ext_vector_type(4)));

__device__ __forceinline__ uint32_t f2bf(float f) {  // RNE fp32 -> bf16
    uint32_t b = __float_as_uint(f);
    return (b + 0x7fffu + ((b >> 16) & 1u)) >> 16;
}

// E [8192][256] fp32 -> XT0 [256][8192] bf16 (transpose via LDS 32x32 tiles)
__global__ __launch_bounds__(256) void cvtE_kernel(const float* __restrict__ E,
                                                   unsigned short* __restrict__ XT) {
    __shared__ float T[32][33];
    const int n0 = blockIdx.x * 32;       // 256 tiles over n
    const int d0 = blockIdx.y * 32;       // 8 tiles over d
    const int t = threadIdx.x;
    const int a = t >> 5, b = t & 31;
    #pragma unroll
    for (int i = 0; i < 4; ++i) {
        int n = i * 8 + a;
        T[b][n] = E[(size_t)(n0 + n) * 256 + d0 + b];   // T[d_local][n_local]
    }
    __syncthreads();
    #pragma unroll
    for (int i = 0; i < 4; ++i) {
        int d = i * 8 + a;
        XT[(size_t)(d0 + d) * NBIG + n0 + b] = (unsigned short)f2bf(T[d][b]);
    }
}

// C[256 x 64-slab] += X[256][K-half] * W-slab. NT=0: W[k][n] (row-major [K][N]);
// NT=1: W'[n][k] (row-major [N][K]). fp32 W converted to bf16 in staging.
// MFMA 16x16x32 bf16. Verified layouts: A[m=lane&15][k=(lane>>4)*8+j],
// B[k][n]: n=lane&15, k=(lane>>4)*8+j (symmetric), C/D: col=lane&15,
// row=(lane>>4)*4+reg.
__global__ __launch_bounds__(256) void gemm_kernel(
        const unsigned short* __restrict__ X,  // [256][8192] bf16
        const float* __restrict__ W,           // [8192][8192] fp32
        float* __restrict__ P,                 // [2][256][8192] fp32 partials
        int NT) {
    __shared__ __align__(16) unsigned short Xlds[MROWS * KP];  // 36 KB
    __shared__ __align__(16) unsigned short Wlds[64 * KP];     // 9 KB
    const int tid  = threadIdx.x;
    const int n0   = blockIdx.x * 64;
    const int ks   = blockIdx.y;
    const int lane = tid & 63;
    const int w    = tid >> 6;
    const int m16  = lane & 15;
    const int q    = lane >> 4;

    float4v acc[16];
    #pragma unroll
    for (int i = 0; i < 16; ++i) acc[i] = (float4v){0.f, 0.f, 0.f, 0.f};

    const int kbeg = ks * (NBIG / 2);
    for (int kb = kbeg; kb < kbeg + NBIG / 2; kb += KC) {
        __syncthreads();                       // protect LDS reuse
        // stage X chunk: 256 rows x 64 cols bf16 = 2048 x 16B
        {
            const uint4* Xg = (const uint4*)X; // 8 bf16 per uint4
            #pragma unroll
            for (int i = 0; i < 8; ++i) {
                int c = tid + i * 256;         // 0..2047
                int m = c >> 3, kq = c & 7;
                uint4 v = Xg[(size_t)m * 1024 + (kb >> 3) + kq];
                *(uint4*)&Xlds[m * KP + kq * 8] = v;
            }
        }
        // stage W slab -> Wlds[n_local][k_local] bf16
        if (NT) {
            const float4* Wg = (const float4*)W;
            #pragma unroll
            for (int i = 0; i < 4; ++i) {
                int c = tid + i * 256;         // 0..1023
                int n = c >> 4, kq = c & 15;   // row n, 4-float chunk kq
                float4 v = Wg[(size_t)(n0 + n) * 2048 + (kb >> 2) + kq];
                uint2 pk;
                pk.x = f2bf(v.x) | (f2bf(v.y) << 16);
                pk.y = f2bf(v.z) | (f2bf(v.w) << 16);
                *(uint2*)&Wlds[n * KP + kq * 4] = pk;
            }
        } else {
            const float4* Wg = (const float4*)W;
            #pragma unroll
            for (int i = 0; i < 4; ++i) {
                int c = tid + i * 256;
                int k = c >> 4, nq = c & 15;   // row kb+k, 4 cols n0+nq*4..
                float4 v = Wg[(size_t)(kb + k) * 2048 + (n0 >> 2) + nq];
                Wlds[(nq * 4 + 0) * KP + k] = (unsigned short)f2bf(v.x);
                Wlds[(nq * 4 + 1) * KP + k] = (unsigned short)f2bf(v.y);
                Wlds[(nq * 4 + 2) * KP + k] = (unsigned short)f2bf(v.z);
                Wlds[(nq * 4 + 3) * KP + k] = (unsigned short)f2bf(v.w);
            }
        }
        __syncthreads();
        // compute: 2 K-steps of 32; wave w owns n-tile w (16 cols), 16 m-tiles
        #pragma unroll
        for (int s = 0; s < 2; ++s) {
            const int k0 = s * 32;
            short8 bf = *(const short8*)&Wlds[(w * 16 + m16) * KP + k0 + q * 8];
            #pragma unroll
            for (int mt = 0; mt < 16; ++mt) {
                short8 af = *(const short8*)&Xlds[(mt * 16 + m16) * KP + k0 + q * 8];
                acc[mt] = __builtin_amdgcn_mfma_f32_16x16x32_bf16(af, bf, acc[mt], 0, 0, 0);
            }
        }
    }
    // epilogue: write fp32 partial
    float* Pp = P + (size_t)ks * PHALF;
    const int col = n0 + w * 16 + m16;
    #pragma unroll
    for (int mt = 0; mt < 16; ++mt) {
        #pragma unroll
        for (int r = 0; r < 4; ++r) {
            int row = mt * 16 + q * 4 + r;
            Pp[(size_t)row * NBIG + col] = acc[mt][r];
        }
    }
}

// P0+P1 -> bf16 X_next [256][8192]
__global__ __launch_bounds__(256) void reduce_mid_kernel(const float* __restrict__ P,
                                                         uint32_t* __restrict__ Xn) {
    int p = blockIdx.x * 256 + threadIdx.x;   // pair index, 1,048,576 total
    int e = p * 2;
    float a = P[e]     + P[e + PHALF];
    float b = P[e + 1] + P[e + 1 + PHALF];
    Xn[p] = f2bf(a) | (f2bf(b) << 16);
}

// P0+P1 -> leaky -> out[n][d] fp32 (transpose via LDS 32x32 tiles)
__global__ __launch_bounds__(256) void reduce_final_kernel(const float* __restrict__ P,
                                                           float* __restrict__ out) {
    __shared__ float T[32][33];
    const int n0 = blockIdx.x * 32;       // 256 tiles over n
    const int d0 = blockIdx.y * 32;       // 8 tiles over d
    const int t = threadIdx.x;
    const int a = t >> 5, b = t & 31;
    #pragma unroll
    for (int i = 0; i < 4; ++i) {
        int d = i * 8 + a;
        size_t idx = (size_t)(d0 + d) * NBIG + n0 + b;
        T[d][b] = P[idx] + P[idx + PHALF];   // T[d_local][n_local]
    }
    __syncthreads();
    #pragma unroll
    for (int i = 0; i < 4; ++i) {
        int n = i * 8 + a;
        float v = T[b][n];
        v = v > 0.f ? v : 0.2f * v;
        out[(size_t)(n0 + n) * 256 + d0 + b] = v;
    }
}

extern "C" void kernel_launch(void* const* d_in, const int* in_sizes, int n_in,
                              void* d_out, int out_size, void* d_ws, size_t ws_size,
                              hipStream_t stream) {
    const float* Bm   = (const float*)d_in[0];  // inp_adj [E, N]
    const float* Am   = (const float*)d_in[1];  // att_adj [N, E]
    const float* embs = (const float*)d_in[2];  // [N, D]
    float* out = (float*)d_out;

    char* w = (char*)d_ws;
    auto alloc = [&](size_t bytes) -> char* {
        char* p = w;
        w += (bytes + 255) & ~(size_t)255;
        return p;
    };
    unsigned short* XT0 = (unsigned short*)alloc((size_t)MROWS * NBIG * 2);  // 4 MB
    unsigned short* XA  = (unsigned short*)alloc((size_t)MROWS * NBIG * 2);  // 4 MB
    unsigned short* XB  = (unsigned short*)alloc((size_t)MROWS * NBIG * 2);  // 4 MB
    float*          P   = (float*)alloc((size_t)2 * PHALF * 4);              // 16 MB

    cvtE_kernel<<<dim3(256, 8), 256, 0, stream>>>(embs, XT0);
    // G1: X1 = XT0 * A (NN)
    gemm_kernel<<<dim3(128, 2), 256, 0, stream>>>(XT0, Am, P, 0);
    reduce_mid_kernel<<<4096, 256, 0, stream>>>(P, (uint32_t*)XA);
    // G2: X2 = X1 * B (NN)
    gemm_kernel<<<dim3(128, 2), 256, 0, stream>>>(XA, Bm, P, 0);
    reduce_mid_kernel<<<4096, 256, 0, stream>>>(P, (uint32_t*)XB);
    // G3: X3 = X2 * B^T (NT)
    gemm_kernel<<<dim3(128, 2), 256, 0, stream>>>(XB, Bm, P, 1);
    reduce_mid_kernel<<<4096, 256, 0, stream>>>(P, (uint32_t*)XA);
    // G4: C4 = X3 * A^T (NT); out = leaky(C4^T)
    gemm_kernel<<<dim3(128, 2), 256, 0, stream>>>(XA, Am, P, 1);
    reduce_final_kernel<<<dim3(256, 8), 256, 0, stream>>>(P, out);

    (void)in_sizes; (void)n_in; (void)out_size; (void)ws_size;
}